// Round 6
// baseline (1000.048 us; speedup 1.0000x reference)
//
#include <hip/hip_runtime.h>
#include <hip/hip_bf16.h>

#define LSPANS 4096
#define BB 32
#define HH 1024
#define DD 1024
#define VV 32000
#define K1 2048   // 2H
#define NT2 250   // V / 128

typedef unsigned short u16;
typedef unsigned char u8;
typedef __attribute__((ext_vector_type(8))) short bf16x8v;
typedef __attribute__((ext_vector_type(4))) float f32x4v;
typedef __attribute__((ext_vector_type(16))) float f32x16v;
typedef __attribute__((ext_vector_type(4))) int i32x4v;
typedef __attribute__((ext_vector_type(8))) int i32x8v;

__device__ __forceinline__ u16 f2bf(float x) {
  union { float f; unsigned u; } v; v.f = x;
  unsigned r = (v.u >> 16) & 1u;
  return (u16)((v.u + 0x7fffu + r) >> 16);
}

// ---------------- prep1: gather span endpoints + cvt W1 (fused) ----------
// blocks [0, LSPANS)            : gather two hidden rows -> bf16 A1[l, 2H]
// blocks [LSPANS, LSPANS+512)   : grid-stride f32->bf16 convert of W1
__global__ void prep1_kernel(const float* __restrict__ hidden,
                             const int* __restrict__ bid,
                             const int* __restrict__ sb,
                             const int* __restrict__ se,
                             u16* __restrict__ A1,
                             const float* __restrict__ W1,
                             u16* __restrict__ W1b) {
  const int blk = blockIdx.x;
  if (blk < LSPANS) {
    const int l = blk;
    const int t = threadIdx.x;  // 256 threads, 4 floats each per half
    const int b = bid[l];
    const float* p0 = hidden + ((size_t)sb[l] * BB + b) * HH;
    const float* p1 = hidden + ((size_t)se[l] * BB + b) * HH;
    u16* dst = A1 + (size_t)l * K1;
    float4 v0 = ((const float4*)p0)[t];
    float4 v1 = ((const float4*)p1)[t];
    ushort4 o0; o0.x = f2bf(v0.x); o0.y = f2bf(v0.y); o0.z = f2bf(v0.z); o0.w = f2bf(v0.w);
    ushort4 o1; o1.x = f2bf(v1.x); o1.y = f2bf(v1.y); o1.z = f2bf(v1.z); o1.w = f2bf(v1.w);
    ((ushort4*)dst)[t]          = o0;
    ((ushort4*)(dst + HH))[t]   = o1;
  } else {
    const int n4 = DD * K1 / 4;
    int i = (blk - LSPANS) * 256 + threadIdx.x;
    const int stride = 512 * 256;
    for (; i < n4; i += stride) {
      float4 v = ((const float4*)W1)[i];
      ushort4 o;
      o.x = f2bf(v.x); o.y = f2bf(v.y); o.z = f2bf(v.z); o.w = f2bf(v.w);
      ((ushort4*)W1b)[i] = o;
    }
  }
}

// ---------------- prep2: GEMM1 (128x64, bf16) + cvt Wout->fp8 (fused) ----
// blocks [0, 512)      : feat = fp8(tanh(A1 @ W1b^T + b1) * 64)
// blocks [512, 2560)   : grid-stride f32->fp8 convert of Wout (x16 scale).
// fp8 pre-scales: feat x64, Wout x16; GEMM2 epilogue multiplies by 2^-10.
__launch_bounds__(256, 2)
__global__ void prep2_kernel(const u16* __restrict__ A, const u16* __restrict__ B,
                             const float* __restrict__ bias,
                             u8* __restrict__ feat_out,
                             const float* __restrict__ Wout,
                             u8* __restrict__ Woutb) {
  __shared__ __align__(16) u16 As[128 * 64];
  __shared__ __align__(16) u16 Bs[64 * 64];

  if (blockIdx.x < 512) {
    const int tid  = threadIdx.x;
    const int lane = tid & 63;
    const int w    = tid >> 6;
    const int wm   = w & 1;
    const int wn   = w >> 1;
    const int q    = lane >> 4;
    const int lm   = lane & 15;
    const int mBase = (blockIdx.x & 31) * 128;   // 32 M-tiles
    const int nBase = (blockIdx.x >> 5) * 64;    // 16 N-tiles

    f32x4v acc[4][2];
#pragma unroll
    for (int i = 0; i < 4; ++i)
#pragma unroll
      for (int j = 0; j < 2; ++j) acc[i][j] = (f32x4v){0.f, 0.f, 0.f, 0.f};

    const int srowA = w * 32 + (lane >> 3);
    const int srowB = w * 16 + (lane >> 3);
    const int scol  = ((lane & 7) ^ (lane >> 3)) * 8;   // swizzled source column
    const u16* Ag = A + (size_t)(mBase + srowA) * K1 + scol;
    const u16* Bg = B + (size_t)(nBase + srowB) * K1 + scol;

    for (int k0 = 0; k0 < K1; k0 += 64) {
#pragma unroll
      for (int c = 0; c < 4; ++c) {
        __builtin_amdgcn_global_load_lds(
            (const __attribute__((address_space(1))) void*)(Ag + k0 + (size_t)c * 8 * K1),
            (__attribute__((address_space(3))) void*)(As + (w * 32 + c * 8) * 64), 16, 0, 0);
      }
#pragma unroll
      for (int c = 0; c < 2; ++c) {
        __builtin_amdgcn_global_load_lds(
            (const __attribute__((address_space(1))) void*)(Bg + k0 + (size_t)c * 8 * K1),
            (__attribute__((address_space(3))) void*)(Bs + (w * 16 + c * 8) * 64), 16, 0, 0);
      }
      __syncthreads();
#pragma unroll
      for (int kk = 0; kk < 64; kk += 32) {
        bf16x8v af[4], bfr[2];
        const int sw = lm & 7;
#pragma unroll
        for (int i = 0; i < 4; ++i) {
          int row = wm * 64 + i * 16 + lm;
          int kch = (kk >> 3) + q;
          af[i] = *(const bf16x8v*)(As + row * 64 + ((kch ^ sw) << 3));
        }
#pragma unroll
        for (int j = 0; j < 2; ++j) {
          int row = wn * 32 + j * 16 + lm;
          int kch = (kk >> 3) + q;
          bfr[j] = *(const bf16x8v*)(Bs + row * 64 + ((kch ^ sw) << 3));
        }
#pragma unroll
        for (int i = 0; i < 4; ++i)
#pragma unroll
          for (int j = 0; j < 2; ++j)
            acc[i][j] = __builtin_amdgcn_mfma_f32_16x16x32_bf16(af[i], bfr[j], acc[i][j], 0, 0, 0);
      }
      __syncthreads();
    }

    float bj[2];
#pragma unroll
    for (int j = 0; j < 2; ++j) bj[j] = bias[nBase + wn * 32 + j * 16 + lm];
#pragma unroll
    for (int i = 0; i < 4; ++i)
#pragma unroll
      for (int j = 0; j < 2; ++j)
#pragma unroll
        for (int r = 0; r < 4; ++r) {
          int tr = wm * 64 + i * 16 + q * 4 + r;
          int tc = wn * 32 + j * 16 + lm;
          float v = tanhf(acc[i][j][r] + bj[j]) * 64.0f;   // fp8 pre-scale 2^6
          int p = __builtin_amdgcn_cvt_pk_fp8_f32(v, v, 0, false);
          feat_out[(size_t)(mBase + tr) * DD + nBase + tc] = (u8)(p & 0xFF);
        }
  } else {
    const int n4 = VV * DD / 4;
    int i = (blockIdx.x - 512) * 256 + threadIdx.x;
    const int stride = 2048 * 256;
    for (; i < n4; i += stride) {
      float4 v = ((const float4*)Wout)[i];
      int p = 0;
      p = __builtin_amdgcn_cvt_pk_fp8_f32(v.x * 16.0f, v.y * 16.0f, p, false);
      p = __builtin_amdgcn_cvt_pk_fp8_f32(v.z * 16.0f, v.w * 16.0f, p, true);
      ((int*)Woutb)[i] = p;
    }
  }
}

// ---------------- 128x128 fp8 MFMA GEMM2 (mfma_scale 32x32x64) ------------
// Same proven m97-style loop/staging/XOR-swizzle as the bf16 kernel, but
// fp8 operands: rows are 1024 B (K=1024 fp8), K-step 128 B = 8 chunks of
// 16 B per row -> identical swizzle geometry (chunk c at LDS slot c^(row&7)).
// MFMA: 32x32x64 f8f6f4, fmt 0 (e4m3), unit HW scales (0x7F); operands
// pre-scaled (feat x64, Wout x16) so logits = acc * 2^-10.
// A-frag: lane holds row=lane&31, k-bytes (lane>>5)*32 + kk*64 .. +31
//   -> two ds_read_b128 at swizzled chunks c^sw, (c+1)^sw.
// C/D: col=lane&31, row=(reg&3)+8*(reg>>2)+4*(lane>>5)  [guide-verified].
__launch_bounds__(256, 2)
__global__ void gemm2_kernel(const u8* __restrict__ A, const u8* __restrict__ B,
                             const int* __restrict__ tags,
                             float* __restrict__ pmax, float* __restrict__ psum,
                             float* __restrict__ ltag) {
  __shared__ __align__(16) u8 As[128 * 128];
  __shared__ __align__(16) u8 Bs[128 * 128];
  __shared__ float rmax[2][128];
  __shared__ float rsum[2][128];
  __shared__ int   stags[128];

  const int tid  = threadIdx.x;
  const int lane = tid & 63;
  const int w    = tid >> 6;       // wave 0..3
  const int wm   = w & 1;          // wave row (M): 64 rows
  const int wn   = w >> 1;         // wave col (N): 64 cols
  const int l5   = lane >> 5;      // k-half selector
  const int lr   = lane & 31;      // row/col within 32-tile
  const int sw   = lr & 7;
  const int mBase = blockIdx.x * 128;
  const int nBase = blockIdx.y * 128;

  if (tid < 128) stags[tid] = tags[mBase + tid];

  f32x16v acc[2][2];
#pragma unroll
  for (int i = 0; i < 2; ++i)
#pragma unroll
    for (int j = 0; j < 2; ++j)
#pragma unroll
      for (int r = 0; r < 16; ++r) acc[i][j][r] = 0.f;

  const int srow = w * 32 + (lane >> 3);
  const int scol = ((lane & 7) ^ (lane >> 3)) * 16;   // swizzled source byte col
  const u8* Ag = A + (size_t)(mBase + srow) * DD + scol;
  const u8* Bg = B + (size_t)(nBase + srow) * DD + scol;

  const int arow = (wm * 64 + lr) * 128;   // byte offset of fragment row
  const int brow = (wn * 64 + lr) * 128;

  for (int k0 = 0; k0 < DD; k0 += 128) {
#pragma unroll
    for (int c = 0; c < 4; ++c) {
      __builtin_amdgcn_global_load_lds(
          (const __attribute__((address_space(1))) void*)(Ag + k0 + (size_t)c * 8 * DD),
          (__attribute__((address_space(3))) void*)(As + (w * 32 + c * 8) * 128), 16, 0, 0);
    }
#pragma unroll
    for (int c = 0; c < 4; ++c) {
      __builtin_amdgcn_global_load_lds(
          (const __attribute__((address_space(1))) void*)(Bg + k0 + (size_t)c * 8 * DD),
          (__attribute__((address_space(3))) void*)(Bs + (w * 32 + c * 8) * 128), 16, 0, 0);
    }
    __syncthreads();
#pragma unroll
    for (int kk = 0; kk < 2; ++kk) {
      const int cb = kk * 4 + l5 * 2;           // even base chunk
      const int o0 = ((cb ^ sw) << 4);
      const int o1 = (((cb + 1) ^ sw) << 4);
      i32x8v af[2], bfv[2];
#pragma unroll
      for (int i = 0; i < 2; ++i) {
        const u8* p = As + arow + i * 4096;     // i*32 rows * 128 B
        i32x4v lo = *(const i32x4v*)(p + o0);
        i32x4v hi = *(const i32x4v*)(p + o1);
        af[i] = __builtin_shufflevector(lo, hi, 0, 1, 2, 3, 4, 5, 6, 7);
      }
#pragma unroll
      for (int j = 0; j < 2; ++j) {
        const u8* p = Bs + brow + j * 4096;
        i32x4v lo = *(const i32x4v*)(p + o0);
        i32x4v hi = *(const i32x4v*)(p + o1);
        bfv[j] = __builtin_shufflevector(lo, hi, 0, 1, 2, 3, 4, 5, 6, 7);
      }
#pragma unroll
      for (int i = 0; i < 2; ++i)
#pragma unroll
        for (int j = 0; j < 2; ++j)
          acc[i][j] = __builtin_amdgcn_mfma_scale_f32_32x32x64_f8f6f4(
              af[i], bfv[j], acc[i][j], 0, 0, 0, 0x7F, 0, 0x7F);
    }
    __syncthreads();
  }

  const float SC = 0.0009765625f;  // 2^-10 undoes feat x64 * Wout x16
  // phase 1: per-row max over this wave's 64 cols -> LDS
#pragma unroll
  for (int i = 0; i < 2; ++i)
#pragma unroll
    for (int r = 0; r < 16; ++r) {
      float m = fmaxf(acc[i][0][r], acc[i][1][r]);
#pragma unroll
      for (int off = 1; off < 32; off <<= 1) m = fmaxf(m, __shfl_xor(m, off, 64));
      if (lr == 0) rmax[wn][wm * 64 + i * 32 + ((r & 3) + 8 * (r >> 2) + 4 * l5)] = m * SC;
    }
  __syncthreads();
  // phase 2: sumexp against the full 128-col row max
#pragma unroll
  for (int i = 0; i < 2; ++i)
#pragma unroll
    for (int r = 0; r < 16; ++r) {
      int tr = wm * 64 + i * 32 + ((r & 3) + 8 * (r >> 2) + 4 * l5);
      float M = fmaxf(rmax[0][tr], rmax[1][tr]);
      float s = __expf(acc[i][0][r] * SC - M) + __expf(acc[i][1][r] * SC - M);
#pragma unroll
      for (int off = 1; off < 32; off <<= 1) s += __shfl_xor(s, off, 64);
      if (lr == 0) rsum[wn][tr] = s;
    }
  __syncthreads();
  if (tid < 128) {
    float M = fmaxf(rmax[0][tid], rmax[1][tid]);
    float S = rsum[0][tid] + rsum[1][tid];
    pmax[(size_t)blockIdx.y * LSPANS + mBase + tid] = M;
    psum[(size_t)blockIdx.y * LSPANS + mBase + tid] = S;
  }
  // tag logit capture (exactly one matching column per row globally)
#pragma unroll
  for (int i = 0; i < 2; ++i)
#pragma unroll
    for (int r = 0; r < 16; ++r) {
      int tr = wm * 64 + i * 32 + ((r & 3) + 8 * (r >> 2) + 4 * l5);
      int tg = stags[tr];
#pragma unroll
      for (int j = 0; j < 2; ++j) {
        int gc = nBase + wn * 64 + j * 32 + lr;
        if (tg == gc) ltag[mBase + tr] = acc[i][j][r] * SC;
      }
    }
}

// ---------------- merge partials, weighted-mean NLL (coalesced online) ------
// pmax/psum layout: [tile t][row l] (t < NT2=250, stride LSPANS).
// 64 blocks x 256 threads; lane = row offset (coalesced). Wave w owns tiles
// t = w, w+4, ... merged with an online max/sum; 4-way combine via LDS.
__global__ void finalize_kernel(const float* __restrict__ pmax, const float* __restrict__ psum,
                                const float* __restrict__ ltag, const int* __restrict__ tags,
                                const float* __restrict__ dprob, float* __restrict__ out) {
  const int lane = threadIdx.x & 63;
  const int wv   = threadIdx.x >> 6;      // 0..3
  const int row  = blockIdx.x * 64 + lane;

  float M = -1e30f, S = 0.f;
  for (int t = wv; t < NT2; t += 4) {
    float pm = pmax[(size_t)t * LSPANS + row];
    float ps = psum[(size_t)t * LSPANS + row];
    float Mn = fmaxf(M, pm);
    S = S * __expf(M - Mn) + ps * __expf(pm - Mn);
    M = Mn;
  }

  __shared__ float lmax[4][64];
  __shared__ float lsum[4][64];
  lmax[wv][lane] = M;
  lsum[wv][lane] = S;
  __syncthreads();

  if (wv == 0) {
    float M0 = fmaxf(fmaxf(lmax[0][lane], lmax[1][lane]),
                     fmaxf(lmax[2][lane], lmax[3][lane]));
    float S0 = lsum[0][lane] * __expf(lmax[0][lane] - M0)
             + lsum[1][lane] * __expf(lmax[1][lane] - M0)
             + lsum[2][lane] * __expf(lmax[2][lane] - M0)
             + lsum[3][lane] * __expf(lmax[3][lane] - M0);
    float nll = M0 + logf(S0) - ltag[row];
    float wgt = 1.0f - dprob[tags[row]];
    float val = nll * wgt * (1.0f / (4096.0f + 1e-5f));
#pragma unroll
    for (int off = 1; off < 64; off <<= 1) val += __shfl_xor(val, off, 64);
    if (lane == 0) atomicAdd(out, val);
  }
}

extern "C" void kernel_launch(void* const* d_in, const int* in_sizes, int n_in,
                              void* d_out, int out_size, void* d_ws, size_t ws_size,
                              hipStream_t stream) {
  const float* hidden = (const float*)d_in[0];
  const float* W1     = (const float*)d_in[1];
  const float* b1     = (const float*)d_in[2];
  const float* Wout   = (const float*)d_in[3];
  const float* dprob  = (const float*)d_in[4];
  const int*   bid    = (const int*)d_in[5];
  const int*   sb     = (const int*)d_in[6];
  const int*   se     = (const int*)d_in[7];
  const int*   tags   = (const int*)d_in[8];
  float* out = (float*)d_out;

  char* ws = (char*)d_ws;
  u16* A1    = (u16*)ws;                 ws += (size_t)LSPANS * K1 * 2;      // 16.78 MB
  u16* W1b   = (u16*)ws;                 ws += (size_t)DD * K1 * 2;          //  4.19 MB
  u8*  Woutb = (u8*)ws;                  ws += (size_t)VV * DD;              // 32.77 MB (fp8)
  u8*  feat  = (u8*)ws;                  ws += (size_t)LSPANS * DD;          //  4.19 MB (fp8)
  float* pmax = (float*)ws;              ws += (size_t)NT2 * LSPANS * 4;     //  4.10 MB
  float* psum = (float*)ws;              ws += (size_t)NT2 * LSPANS * 4;     //  4.10 MB
  float* ltag = (float*)ws;              ws += (size_t)LSPANS * 4;

  hipMemsetAsync(d_out, 0, sizeof(float), stream);

  // prep1: gather span endpoints + cvt W1 (fused)
  prep1_kernel<<<LSPANS + 512, 256, 0, stream>>>(hidden, bid, sb, se, A1, W1, W1b);

  // prep2: GEMM1 (512 blocks) + cvt Wout -> fp8 (2048 grid-stride)
  prep2_kernel<<<512 + 2048, 256, 0, stream>>>(A1, W1b, b1, feat, Wout, Woutb);

  // GEMM2: fp8 logits tiles + fused softmax partials   [4096 x 32000]
  gemm2_kernel<<<dim3(LSPANS / 128, NT2), 256, 0, stream>>>(
      feat, Woutb, tags, pmax, psum, ltag);

  // merge + weighted mean
  finalize_kernel<<<LSPANS / 64, 256, 0, stream>>>(pmax, psum, ltag, tags, dprob, out);
}